// Round 2
// baseline (2204.492 us; speedup 1.0000x reference)
//
#include <hip/hip_runtime.h>

// FSMN depthwise strided FIR — unified-stream software-pipelined version.
// B=32, T=2000, D=512, L_ORDER=R_ORDER=20, strides=2.
//
// Parity decomposition (xe[s]=x[2s], xo[s]=x[2s+1]):
//   out[b,2m  ,d] = sum_i fL[i]*xe[m-20+i] + sum_j fR[j]*xo[m+j]
//   out[b,2m+1,d] = sum_i fL[i]*xo[m-20+i] + sum_j fR[j]*xe[m+1+j]
//
// Key observation: with k = s-(m0-20), the E-window for BOTH passes is
// k = t..t+M-1 at unified step t=0..40 (tap row = filt[t] for all t);
// the O-window is the same except it skips its shift at t=20.
// => one 41-step sweep, single sliding window per parity, with explicit
// prefetch queues (depth P_=2) for data AND filter loads, plus a 14-load
// prologue burst. Prefetch distance ~2 steps (~64 FMA4s) hides L2 latency;
// previous version had distance ~0 (edge load used next iter, filt used
// immediately) -> serial ~500cy stall per load, VALUBusy 11%.
//
// R4 history: R3 (M_=5, two-pass, dist-0) = 206us/dispatch, VALU 11%,
//             occ 15%, HBM 28% -> latency-bound.
// R5: fix nontemporal builtin type (needs clang ext_vector, not HIP_vector_type).

#define B_ 32
#define T_ 2000
#define D_ 512
#define S_ 1000   // T/2
#define M_ 4      // m-positions per thread (=> 8 output rows)
#define P_ 2      // data prefetch queue depth (steps)
#define FP_ 2     // filter prefetch queue depth (steps)

typedef float nf4 __attribute__((ext_vector_type(4)));  // native vec for builtins

__device__ __forceinline__ float4 zf4() {
    float4 z; z.x = 0.f; z.y = 0.f; z.z = 0.f; z.w = 0.f; return z;
}

__device__ __forceinline__ void fma4(float4& a, const float4 f, const float4 w) {
    a.x = fmaf(f.x, w.x, a.x);
    a.y = fmaf(f.y, w.y, a.y);
    a.z = fmaf(f.z, w.z, a.z);
    a.w = fmaf(f.w, w.w, a.w);
}

__device__ __forceinline__ void st_nt(float* p, const float4 v) {
    __builtin_nontemporal_store(*(const nf4*)&v, (nf4*)p);
}

template<bool CHK>
__device__ __forceinline__ void fsmn_body(const float* __restrict__ xb,
                                          const float* __restrict__ fb,
                                          float* __restrict__ ob, int m0)
{
    // Streams: E consumes k=0..M_+39 (s=m0-20+k, row 2s); O consumes k=0..M_+38 (row 2s+1).
    auto ldE = [&](int k) -> float4 {
        int s = m0 - 20 + k;
        if (!CHK || (unsigned)s < (unsigned)S_)
            return *(const float4*)(xb + (size_t)(2 * s) * D_);
        return zf4();
    };
    auto ldO = [&](int k) -> float4 {
        int s = m0 - 20 + k;
        if (!CHK || (unsigned)s < (unsigned)S_)
            return *(const float4*)(xb + (size_t)(2 * s + 1) * D_);
        return zf4();
    };

    float4 ae[M_], ao[M_];
#pragma unroll
    for (int m = 0; m < M_; ++m) { ae[m] = zf4(); ao[m] = zf4(); }

    float4 wE[M_], wO[M_];   // sliding windows
    float4 qE[P_], qO[P_];   // data prefetch queues
    float4 qF[FP_];          // filter prefetch queue

    // ---- Prologue burst: 2*(M_+P_)+FP_ = 14 independent loads in flight ----
#pragma unroll
    for (int m = 0; m < M_; ++m) wE[m] = ldE(m);
#pragma unroll
    for (int m = 0; m < M_; ++m) wO[m] = ldO(m);
#pragma unroll
    for (int p = 0; p < P_; ++p) qE[p] = ldE(M_ + p);
#pragma unroll
    for (int p = 0; p < P_; ++p) qO[p] = ldO(M_ + p);
#pragma unroll
    for (int p = 0; p < FP_; ++p) qF[p] = *(const float4*)(fb + (size_t)p * D_);

    // ---- Unified 41-step sweep ----
#pragma unroll
    for (int t = 0; t < 41; ++t) {
        // 1. issue this step's prefetch loads FIRST (consumed at step t+P_)
        float4 tE = zf4(), tO = zf4(), tF = zf4();
        const bool doE = (t <= 39 - P_);                       // kE = t+M_+P_ <= M_+39
        const bool doO = (t != 20) &&
                         ((t <= 19) ? true : (t <= 39 - P_));  // kO <= M_+38
        if (doE) tE = ldE(t + M_ + P_);
        if (doO) tO = ldO(((t <= 19) ? t : t - 1) + M_ + P_);
        if (t + FP_ <= 40) tF = *(const float4*)(fb + (size_t)(t + FP_) * D_);

        // 2. FMAs on data loaded >= P_ steps ago
        const float4 fv = qF[0];
        if (t < 21) {   // left taps fL[t]
#pragma unroll
            for (int m = 0; m < M_; ++m) { fma4(ae[m], fv, wE[m]); fma4(ao[m], fv, wO[m]); }
        } else {        // right taps fR[t-21]
#pragma unroll
            for (int m = 0; m < M_; ++m) { fma4(ao[m], fv, wE[m]); fma4(ae[m], fv, wO[m]); }
        }

        // 3. shifts (pure register renaming under full unroll)
#pragma unroll
        for (int p = 0; p < FP_ - 1; ++p) qF[p] = qF[p + 1];
        qF[FP_ - 1] = tF;
        if (t < 40) {
#pragma unroll
            for (int m = 0; m < M_ - 1; ++m) wE[m] = wE[m + 1];
            wE[M_ - 1] = qE[0];
#pragma unroll
            for (int p = 0; p < P_ - 1; ++p) qE[p] = qE[p + 1];
            qE[P_ - 1] = tE;
            if (t != 20) {  // O window holds still across the left->right junction
#pragma unroll
                for (int m = 0; m < M_ - 1; ++m) wO[m] = wO[m + 1];
                wO[M_ - 1] = qO[0];
#pragma unroll
                for (int p = 0; p < P_ - 1; ++p) qO[p] = qO[p + 1];
                qO[P_ - 1] = tO;
            }
        }
    }

    // ---- Store 2*M_ output rows; nontemporal: output is never re-read,
    //      keep it from evicting the x halo out of L2. ----
#pragma unroll
    for (int m = 0; m < M_; ++m) {
        if (!CHK || (m0 + m) < S_) {
            st_nt(ob + (size_t)(2 * (m0 + m))     * D_, ae[m]);
            st_nt(ob + (size_t)(2 * (m0 + m) + 1) * D_, ao[m]);
        }
    }
}

__global__ __launch_bounds__(256, 4) void fsmn_kernel(
    const float* __restrict__ x, const float* __restrict__ filt,
    float* __restrict__ out)
{
    const int d4 = threadIdx.x;            // 0..63 : float4 index within d-half
    const int mg = threadIdx.y;            // 0..3  : m-group (one wave each)

    // XCD-chunked swizzle: 4096 blocks = 8 XCDs x 512. Consecutive-mb blocks
    // (which share the 40-row halo) land on the SAME XCD's L2.
    const int bid  = blockIdx.x;           // 0..4095
    const int xcd  = bid & 7;
    const int slot = bid >> 3;
    const int n    = xcd * 512 + slot;     // linear id, mb-fastest
    const int mb   = n & 63;               // 0..63 : m-block
    const int rest = n >> 6;
    const int dh   = rest & 1;             // 0..1  : d-half
    const int b    = rest >> 1;            // 0..31 : batch

    const int m0 = (mb * 4 + mg) * M_;
    if (m0 >= S_) return;                  // tail pad blocks

    const int d = (dh * 64 + d4) * 4;
    const float* xb = x + (size_t)b * T_ * D_ + d;
    const float* fb = filt + d;
    float*       ob = out + (size_t)b * T_ * D_ + d;

    // Interior iff every stream index is in [0, S_): E spans [m0-20, m0+M_+19].
    const bool interior = (m0 >= 20) && (m0 <= S_ - M_ - 20);
    if (interior) fsmn_body<false>(xb, fb, ob, m0);
    else          fsmn_body<true >(xb, fb, ob, m0);
}

extern "C" void kernel_launch(void* const* d_in, const int* in_sizes, int n_in,
                              void* d_out, int out_size, void* d_ws, size_t ws_size,
                              hipStream_t stream) {
    const float* x    = (const float*)d_in[0];
    const float* filt = (const float*)d_in[1];
    float*       out  = (float*)d_out;

    dim3 block(64, 4, 1);
    // ceil(250 m-groups / 4 per block) = 63 -> pad to 64 for a bijective
    // 8-XCD chunk swizzle: 64 x 2 x 32 = 4096 blocks.
    dim3 grid(4096, 1, 1);
    hipLaunchKernelGGL(fsmn_kernel, grid, block, 0, stream, x, filt, out);
}

// Round 3
// 1758.927 us; speedup vs baseline: 1.2533x; 1.2533x over previous
//
#include <hip/hip_runtime.h>

// FSMN depthwise strided FIR — unified-stream pipeline in the proven
// two-loop skeleton. B=32, T=2000, D=512, L=R=20, strides=2.
//
// Parity decomposition (xe[s]=x[2s], xo[s]=x[2s+1]), k index: s = m0-20+k.
//   step t=0..40 uses tap filt[t]; E-window k=t..t+M-1 for ALL t;
//   O-window k=t..t+M-1 for t<=20, k=t-1..t+M-2 for t>=21 (holds at t=20).
//   t<=20: ae+=f*E, ao+=f*O.   t>=21: ao+=f*E, ae+=f*O.
//
// R2 post-mortem: single fused 41-step loop with runtime-varying control
// did NOT unroll -> register arrays demoted to scratch (VGPR=64, FETCH
// 4.4 GB, WRITE 2.6 GB, VALU 1.3%, 2081us). Fix: express the same
// pipeline (prefetch distance 2 for data AND filter) in the two-loop
// structure that is known to unroll (R3 baseline): left t=0..19 uniform,
// peeled junction t=20, right u=0..19 with compile-time tail guards.
// Unroll-success tell: VGPR_Count ~100-140 (64 again = failed).

#define B_ 32
#define T_ 2000
#define D_ 512
#define S_ 1000   // T/2
#define M_ 4      // m-positions per thread (=> 8 output rows)

typedef float nf4 __attribute__((ext_vector_type(4)));  // native vec for builtins

__device__ __forceinline__ float4 zf4() {
    float4 z; z.x = 0.f; z.y = 0.f; z.z = 0.f; z.w = 0.f; return z;
}

__device__ __forceinline__ void fma4(float4& a, const float4 f, const float4 w) {
    a.x = fmaf(f.x, w.x, a.x);
    a.y = fmaf(f.y, w.y, a.y);
    a.z = fmaf(f.z, w.z, a.z);
    a.w = fmaf(f.w, w.w, a.w);
}

__device__ __forceinline__ void st_nt(float* p, const float4 v) {
    __builtin_nontemporal_store(*(const nf4*)&v, (nf4*)p);
}

template<bool CHK>
__device__ __forceinline__ void fsmn_body(const float* __restrict__ xb,
                                          const float* __restrict__ fb,
                                          float* __restrict__ ob, int m0)
{
    // E consumes k=0..M_+39 (row 2s), O consumes k=0..M_+38 (row 2s+1).
    auto ldE = [&](int k) -> float4 {
        int s = m0 - 20 + k;
        if (!CHK || (unsigned)s < (unsigned)S_)
            return *(const float4*)(xb + (size_t)(2 * s) * D_);
        return zf4();
    };
    auto ldO = [&](int k) -> float4 {
        int s = m0 - 20 + k;
        if (!CHK || (unsigned)s < (unsigned)S_)
            return *(const float4*)(xb + (size_t)(2 * s + 1) * D_);
        return zf4();
    };
    auto ldF = [&](int t) -> float4 {
        return *(const float4*)(fb + (size_t)t * D_);
    };

    float4 ae[M_], ao[M_];
#pragma unroll
    for (int m = 0; m < M_; ++m) { ae[m] = zf4(); ao[m] = zf4(); }

    float4 wE[M_], wO[M_];   // sliding windows (k = t+m / O variant)
    float4 qE[2], qO[2];     // data prefetch queues, distance 2 steps
    float4 qF[2];            // filter prefetch queue, distance 2 steps

    // ---- Prologue burst: 14 independent loads in flight ----
#pragma unroll
    for (int m = 0; m < M_; ++m) wE[m] = ldE(m);
#pragma unroll
    for (int m = 0; m < M_; ++m) wO[m] = ldO(m);
    qE[0] = ldE(M_);     qE[1] = ldE(M_ + 1);
    qO[0] = ldO(M_);     qO[1] = ldO(M_ + 1);
    qF[0] = ldF(0);      qF[1] = ldF(1);

    // ---- Left loop t=0..19 (uniform body; shifts E, O, F every step) ----
#pragma unroll
    for (int t = 0; t < 20; ++t) {
        // loads issued 2 steps before use
        float4 tE = ldE(t + M_ + 2);
        float4 tO = ldO(t + M_ + 2);
        float4 tF = ldF(t + 2);
        const float4 fv = qF[0];                 // filt[t]
#pragma unroll
        for (int m = 0; m < M_; ++m) { fma4(ae[m], fv, wE[m]); fma4(ao[m], fv, wO[m]); }
#pragma unroll
        for (int m = 0; m < M_ - 1; ++m) { wE[m] = wE[m + 1]; wO[m] = wO[m + 1]; }
        wE[M_ - 1] = qE[0];  qE[0] = qE[1];  qE[1] = tE;
        wO[M_ - 1] = qO[0];  qO[0] = qO[1];  qO[1] = tO;
        qF[0] = qF[1];  qF[1] = tF;
    }

    // ---- Junction t=20: tap filt[20]; E and F shift, O holds ----
    {
        float4 tE = ldE(20 + M_ + 2);
        float4 tF = ldF(22);
        const float4 fv = qF[0];                 // filt[20]
#pragma unroll
        for (int m = 0; m < M_; ++m) { fma4(ae[m], fv, wE[m]); fma4(ao[m], fv, wO[m]); }
#pragma unroll
        for (int m = 0; m < M_ - 1; ++m) wE[m] = wE[m + 1];
        wE[M_ - 1] = qE[0];  qE[0] = qE[1];  qE[1] = tE;
        qF[0] = qF[1];  qF[1] = tF;
    }

    // ---- Right loop u=0..19 (t=21+u): swapped accumulation ----
#pragma unroll
    for (int u = 0; u < 20; ++u) {
        float4 tE = zf4(), tO = zf4(), tF = zf4();
        if (u <= 16) {                           // kE=M_+23+u<=M_+39, kO=M_+22+u<=M_+38
            tE = ldE(M_ + 23 + u);
            tO = ldO(M_ + 22 + u);
        }
        if (u <= 17) tF = ldF(23 + u);           // filt index <= 40
        const float4 fv = qF[0];                 // filt[21+u]
#pragma unroll
        for (int m = 0; m < M_; ++m) { fma4(ao[m], fv, wE[m]); fma4(ae[m], fv, wO[m]); }
        if (u < 19) {
#pragma unroll
            for (int m = 0; m < M_ - 1; ++m) { wE[m] = wE[m + 1]; wO[m] = wO[m + 1]; }
            wE[M_ - 1] = qE[0];  qE[0] = qE[1];  qE[1] = tE;
            wO[M_ - 1] = qO[0];  qO[0] = qO[1];  qO[1] = tO;
            qF[0] = qF[1];  qF[1] = tF;
        }
    }

    // ---- Store 2*M_ output rows (nontemporal: output never re-read) ----
#pragma unroll
    for (int m = 0; m < M_; ++m) {
        if (!CHK || (m0 + m) < S_) {
            st_nt(ob + (size_t)(2 * (m0 + m))     * D_, ae[m]);
            st_nt(ob + (size_t)(2 * (m0 + m) + 1) * D_, ao[m]);
        }
    }
}

__global__ __launch_bounds__(256, 3) void fsmn_kernel(
    const float* __restrict__ x, const float* __restrict__ filt,
    float* __restrict__ out)
{
    const int d4 = threadIdx.x;            // 0..63 : float4 index within d-half
    const int mg = threadIdx.y;            // 0..3  : m-group (one wave each)

    // XCD-chunked swizzle: 4032 blocks = 8 XCDs x 504 (bijective).
    // Consecutive-mb blocks (sharing the 40-row halo) land on one XCD's L2.
    const int bid  = blockIdx.x;           // 0..4031
    const int xcd  = bid & 7;
    const int slot = bid >> 3;
    const int n    = xcd * 504 + slot;     // linear id, mb-fastest
    const int mb   = n % 63;               // 0..62 : m-block
    const int rest = n / 63;               // 0..63
    const int dh   = rest & 1;             // 0..1  : d-half
    const int b    = rest >> 1;            // 0..31 : batch

    const int m0 = (mb * 4 + mg) * M_;
    if (m0 >= S_) return;                  // tail wave slots

    const int d = (dh * 64 + d4) * 4;
    const float* xb = x + (size_t)b * T_ * D_ + d;
    const float* fb = filt + d;
    float*       ob = out + (size_t)b * T_ * D_ + d;

    // Interior iff every stream index is in [0, S_): E spans [m0-20, m0+M_+19].
    const bool interior = (m0 >= 20) && (m0 <= S_ - M_ - 20);
    if (interior) fsmn_body<false>(xb, fb, ob, m0);
    else          fsmn_body<true >(xb, fb, ob, m0);
}

extern "C" void kernel_launch(void* const* d_in, const int* in_sizes, int n_in,
                              void* d_out, int out_size, void* d_ws, size_t ws_size,
                              hipStream_t stream) {
    const float* x    = (const float*)d_in[0];
    const float* filt = (const float*)d_in[1];
    float*       out  = (float*)d_out;

    dim3 block(64, 4, 1);
    // 63 m-blocks (16 m per block) x 2 d-halves x 32 batches = 4032 blocks.
    dim3 grid(4032, 1, 1);
    hipLaunchKernelGGL(fsmn_kernel, grid, block, 0, stream, x, filt, out);
}

// Round 4
// 404.023 us; speedup vs baseline: 5.4564x; 4.3535x over previous
//
#include <hip/hip_runtime.h>

// FSMN depthwise strided FIR — unified-stream pipeline, spill-safe config.
// B=32, T=2000, D=512, L=R=20, strides=2.
//
// Parity decomposition (xe[s]=x[2s], xo[s]=x[2s+1]), k index: s = m0-20+k.
//   step t=0..40 uses tap filt[t]; E-window k=t..t+M-1 for ALL t;
//   O-window k=t..t+M-1 for t<=20, k=t-1..t+M-2 for t>=21 (holds at t=20).
//   t<=20: ae+=f*E, ao+=f*O.   t>=21: ao+=f*E, ae+=f*O.
//
// Spill history (the real enemy so far — pipeline never actually ran):
//   R2: fused 41-step loop, runtime control -> no unroll -> scratch. 2081us.
//   R3: two-loop skeleton OK, but launch_bounds(256,3) caps VGPR at ~170;
//       live set ~160-170 -> RA spilled window arrays wholesale (reported
//       VGPR=84, FETCH 2.9GB, WRITE 2.1GB, VALU 1.6%). 1633us.
//   R4: launch_bounds(256,2) (cap 256, baseline-proven) + plain float4
//       stores (drop type-punned NT builtin, possible SROA blocker).
//       Success tell: VGPR 140-190 and FETCH ~0.3GB.

#define B_ 32
#define T_ 2000
#define D_ 512
#define S_ 1000   // T/2
#define M_ 4      // m-positions per thread (=> 8 output rows)

__device__ __forceinline__ float4 zf4() {
    float4 z; z.x = 0.f; z.y = 0.f; z.z = 0.f; z.w = 0.f; return z;
}

__device__ __forceinline__ void fma4(float4& a, const float4 f, const float4 w) {
    a.x = fmaf(f.x, w.x, a.x);
    a.y = fmaf(f.y, w.y, a.y);
    a.z = fmaf(f.z, w.z, a.z);
    a.w = fmaf(f.w, w.w, a.w);
}

template<bool CHK>
__device__ __forceinline__ void fsmn_body(const float* __restrict__ xb,
                                          const float* __restrict__ fb,
                                          float* __restrict__ ob, int m0)
{
    // E consumes k=0..M_+39 (row 2s), O consumes k=0..M_+38 (row 2s+1).
    auto ldE = [&](int k) -> float4 {
        int s = m0 - 20 + k;
        if (!CHK || (unsigned)s < (unsigned)S_)
            return *(const float4*)(xb + (size_t)(2 * s) * D_);
        return zf4();
    };
    auto ldO = [&](int k) -> float4 {
        int s = m0 - 20 + k;
        if (!CHK || (unsigned)s < (unsigned)S_)
            return *(const float4*)(xb + (size_t)(2 * s + 1) * D_);
        return zf4();
    };
    auto ldF = [&](int t) -> float4 {
        return *(const float4*)(fb + (size_t)t * D_);
    };

    float4 ae[M_], ao[M_];
#pragma unroll
    for (int m = 0; m < M_; ++m) { ae[m] = zf4(); ao[m] = zf4(); }

    float4 wE[M_], wO[M_];   // sliding windows (k = t+m / O variant)
    float4 qE[2], qO[2];     // data prefetch queues, distance 2 steps
    float4 qF[2];            // filter prefetch queue, distance 2 steps

    // ---- Prologue burst: 14 independent loads in flight ----
#pragma unroll
    for (int m = 0; m < M_; ++m) wE[m] = ldE(m);
#pragma unroll
    for (int m = 0; m < M_; ++m) wO[m] = ldO(m);
    qE[0] = ldE(M_);     qE[1] = ldE(M_ + 1);
    qO[0] = ldO(M_);     qO[1] = ldO(M_ + 1);
    qF[0] = ldF(0);      qF[1] = ldF(1);

    // ---- Left loop t=0..19 (uniform body; shifts E, O, F every step) ----
#pragma unroll
    for (int t = 0; t < 20; ++t) {
        // loads issued 2 steps before use
        float4 tE = ldE(t + M_ + 2);
        float4 tO = ldO(t + M_ + 2);
        float4 tF = ldF(t + 2);
        const float4 fv = qF[0];                 // filt[t]
#pragma unroll
        for (int m = 0; m < M_; ++m) { fma4(ae[m], fv, wE[m]); fma4(ao[m], fv, wO[m]); }
#pragma unroll
        for (int m = 0; m < M_ - 1; ++m) { wE[m] = wE[m + 1]; wO[m] = wO[m + 1]; }
        wE[M_ - 1] = qE[0];  qE[0] = qE[1];  qE[1] = tE;
        wO[M_ - 1] = qO[0];  qO[0] = qO[1];  qO[1] = tO;
        qF[0] = qF[1];  qF[1] = tF;
    }

    // ---- Junction t=20: tap filt[20]; E and F shift, O holds ----
    {
        float4 tE = ldE(20 + M_ + 2);
        float4 tF = ldF(22);
        const float4 fv = qF[0];                 // filt[20]
#pragma unroll
        for (int m = 0; m < M_; ++m) { fma4(ae[m], fv, wE[m]); fma4(ao[m], fv, wO[m]); }
#pragma unroll
        for (int m = 0; m < M_ - 1; ++m) wE[m] = wE[m + 1];
        wE[M_ - 1] = qE[0];  qE[0] = qE[1];  qE[1] = tE;
        qF[0] = qF[1];  qF[1] = tF;
    }

    // ---- Right loop u=0..19 (t=21+u): swapped accumulation ----
#pragma unroll
    for (int u = 0; u < 20; ++u) {
        float4 tE = zf4(), tO = zf4(), tF = zf4();
        if (u <= 16) {                           // kE=27+u<=43, kO=26+u<=42
            tE = ldE(M_ + 23 + u);
            tO = ldO(M_ + 22 + u);
        }
        if (u <= 17) tF = ldF(23 + u);           // filt index <= 40
        const float4 fv = qF[0];                 // filt[21+u]
#pragma unroll
        for (int m = 0; m < M_; ++m) { fma4(ao[m], fv, wE[m]); fma4(ae[m], fv, wO[m]); }
        if (u < 19) {
#pragma unroll
            for (int m = 0; m < M_ - 1; ++m) { wE[m] = wE[m + 1]; wO[m] = wO[m + 1]; }
            wE[M_ - 1] = qE[0];  qE[0] = qE[1];  qE[1] = tE;
            wO[M_ - 1] = qO[0];  qO[0] = qO[1];  qO[1] = tO;
            qF[0] = qF[1];  qF[1] = tF;
        }
    }

    // ---- Store 2*M_ output rows (coalesced float4 across 64 lanes) ----
#pragma unroll
    for (int m = 0; m < M_; ++m) {
        if (!CHK || (m0 + m) < S_) {
            *(float4*)(ob + (size_t)(2 * (m0 + m))     * D_) = ae[m];
            *(float4*)(ob + (size_t)(2 * (m0 + m) + 1) * D_) = ao[m];
        }
    }
}

__global__ __launch_bounds__(256, 2) void fsmn_kernel(
    const float* __restrict__ x, const float* __restrict__ filt,
    float* __restrict__ out)
{
    const int d4 = threadIdx.x;            // 0..63 : float4 index within d-half
    const int mg = threadIdx.y;            // 0..3  : m-group (one wave each)

    // XCD-chunked swizzle: 4032 blocks = 8 XCDs x 504 (bijective).
    // Consecutive-mb blocks (sharing the 40-row halo) land on one XCD's L2.
    const int bid  = blockIdx.x;           // 0..4031
    const int xcd  = bid & 7;
    const int slot = bid >> 3;
    const int n    = xcd * 504 + slot;     // linear id, mb-fastest
    const int mb   = n % 63;               // 0..62 : m-block
    const int rest = n / 63;               // 0..63
    const int dh   = rest & 1;             // 0..1  : d-half
    const int b    = rest >> 1;            // 0..31 : batch

    const int m0 = (mb * 4 + mg) * M_;
    if (m0 >= S_) return;                  // tail wave slots

    const int d = (dh * 64 + d4) * 4;
    const float* xb = x + (size_t)b * T_ * D_ + d;
    const float* fb = filt + d;
    float*       ob = out + (size_t)b * T_ * D_ + d;

    // Interior iff every stream index is in [0, S_): E spans [m0-20, m0+M_+19].
    const bool interior = (m0 >= 20) && (m0 <= S_ - M_ - 20);
    if (interior) fsmn_body<false>(xb, fb, ob, m0);
    else          fsmn_body<true >(xb, fb, ob, m0);
}

extern "C" void kernel_launch(void* const* d_in, const int* in_sizes, int n_in,
                              void* d_out, int out_size, void* d_ws, size_t ws_size,
                              hipStream_t stream) {
    const float* x    = (const float*)d_in[0];
    const float* filt = (const float*)d_in[1];
    float*       out  = (float*)d_out;

    dim3 block(64, 4, 1);
    // 63 m-blocks (16 m per block) x 2 d-halves x 32 batches = 4032 blocks.
    dim3 grid(4032, 1, 1);
    hipLaunchKernelGGL(fsmn_kernel, grid, block, 0, stream, x, filt, out);
}

// Round 5
// 363.077 us; speedup vs baseline: 6.0717x; 1.1128x over previous
//
#include <hip/hip_runtime.h>

// FSMN depthwise strided FIR — batched-MLP register kernel.
// B=32, T=2000, D=512, L=R=20, strides=2.
//
// Parity decomposition (xe[s]=x[2s], xo[s]=x[2s+1]), k index: s = m0-20+k.
//   step t=0..40 uses tap filt[t]; E-window k=t..t+3; O-window k=t..t+3
//   (t<=20) / k=t-1..t+2 (t>=21, holds at t=20).
//   t<=20: ae+=f*E, ao+=f*O.   t>=21: ao+=f*E, ae+=f*O.
//
// R4 post-mortem: dist-2 queues gave NO win (263us vs 206 baseline).
// Little's law on measured 1.6 TB/s => only ~2 wave-loads outstanding
// per CU; compiler waitcnt discipline drains deeper than source dist-2,
// and L3-served loads still cost ~500-900cy latency. Fix: BATCHED
// issue/consume. Batch p+1's 12 loads are issued before ANY use of
// batch p => in-order vmcnt GUARANTEES >=12 outstanding at every
// consume point. 8-10 waves/CU x 12KB ≈ 100KB/CU in flight >> 22KB
// Little's-law need for full BW share.
//
// Spill ledger: R2 fused-loop no-unroll (VGPR 64, 2081us); R3 lb(256,3)
// cap 170 < live set (VGPR 84, 1633us); R4 lb(256,2) clean (VGPR 128).
// R5 live set ~185 -> lb(256,1) (cap 512). Spill tell: VGPR<=100.

#define B_ 32
#define T_ 2000
#define D_ 512
#define S_ 1000   // T/2
#define M_ 4      // m-positions per thread (=> 8 output rows)

__device__ __forceinline__ float4 zf4() {
    float4 z; z.x = 0.f; z.y = 0.f; z.z = 0.f; z.w = 0.f; return z;
}

__device__ __forceinline__ void fma4(float4& a, const float4 f, const float4 w) {
    a.x = fmaf(f.x, w.x, a.x);
    a.y = fmaf(f.y, w.y, a.y);
    a.z = fmaf(f.z, w.z, a.z);
    a.w = fmaf(f.w, w.w, a.w);
}

template<bool CHK>
__device__ __forceinline__ void fsmn_body(const float* __restrict__ xb,
                                          const float* __restrict__ fb,
                                          float* __restrict__ ob, int m0)
{
    // E values k=0..43 (row 2s), O values k=0..42 (row 2s+1), s=m0-20+k.
    auto ldE = [&](int k) -> float4 {
        int s = m0 - 20 + k;
        if (!CHK || (unsigned)s < (unsigned)S_)
            return *(const float4*)(xb + (size_t)(2 * s) * D_);
        return zf4();
    };
    auto ldO = [&](int k) -> float4 {
        int s = m0 - 20 + k;
        if (!CHK || (unsigned)s < (unsigned)S_)
            return *(const float4*)(xb + (size_t)(2 * s + 1) * D_);
        return zf4();
    };
    auto ldF = [&](int t) -> float4 {
        return *(const float4*)(fb + (size_t)t * D_);
    };

    float4 ae[M_], ao[M_];
#pragma unroll
    for (int m = 0; m < M_; ++m) { ae[m] = zf4(); ao[m] = zf4(); }

    float4 wE[M_], wO[M_];          // sliding windows
    float4 bE[2][4], bO[2][4], bF[2][4];  // double-buffered load batches

    // ---- Prologue burst: 8 window + 12 batch-0 loads in flight ----
#pragma unroll
    for (int m = 0; m < M_; ++m) wE[m] = ldE(m);
#pragma unroll
    for (int m = 0; m < M_; ++m) wO[m] = ldO(m);
#pragma unroll
    for (int j = 0; j < 4; ++j) {
        bE[0][j] = ldE(j + 4);
        bO[0][j] = ldO(j + 4);
        bF[0][j] = ldF(j);
    }

    // ---- Batch loop: batch p = steps t=4p..4p+3 (p=0..9), p=10 = step 40 ----
#pragma unroll
    for (int p = 0; p <= 10; ++p) {
        // 1. ISSUE batch p+1 (guarantees >=12 outstanding during consume of p)
        const int q = p + 1;
        if (q <= 9) {
#pragma unroll
            for (int j = 0; j < 4; ++j) {
                const int t = 4 * q + j;                  // 4..39, compile-time
                bE[q & 1][j] = ldE(t + 4);                // E edge k=t+4 (<=43)
                if (t != 20)
                    bO[q & 1][j] = ldO(t < 20 ? t + 4 : t + 3);  // k<=42
                bF[q & 1][j] = ldF(t);
            }
        } else if (q == 10) {
            bF[0][0] = ldF(40);                           // step-40 tap only
        }

        // 2. CONSUME batch p (values issued one batch ago)
#pragma unroll
        for (int j = 0; j < 4; ++j) {
            const int t = 4 * p + j;                      // compile-time
            if (t <= 40) {
                const float4 fv = bF[p & 1][j];           // filt[t]
                if (t <= 20) {
#pragma unroll
                    for (int m = 0; m < M_; ++m) { fma4(ae[m], fv, wE[m]); fma4(ao[m], fv, wO[m]); }
                } else {
#pragma unroll
                    for (int m = 0; m < M_; ++m) { fma4(ao[m], fv, wE[m]); fma4(ae[m], fv, wO[m]); }
                }
                if (t < 40) {
#pragma unroll
                    for (int m = 0; m < M_ - 1; ++m) wE[m] = wE[m + 1];
                    wE[M_ - 1] = bE[p & 1][j];            // push k=t+4
                    if (t != 20) {                        // O holds at junction
#pragma unroll
                        for (int m = 0; m < M_ - 1; ++m) wO[m] = wO[m + 1];
                        wO[M_ - 1] = bO[p & 1][j];        // push k=t+4 / t+3
                    }
                }
            }
        }
    }

    // ---- Store 2*M_ output rows (coalesced float4 across 64 lanes) ----
#pragma unroll
    for (int m = 0; m < M_; ++m) {
        if (!CHK || (m0 + m) < S_) {
            *(float4*)(ob + (size_t)(2 * (m0 + m))     * D_) = ae[m];
            *(float4*)(ob + (size_t)(2 * (m0 + m) + 1) * D_) = ao[m];
        }
    }
}

__global__ __launch_bounds__(256, 1) void fsmn_kernel(
    const float* __restrict__ x, const float* __restrict__ filt,
    float* __restrict__ out)
{
    const int d4 = threadIdx.x;            // 0..63 : float4 index within d-half
    const int mg = threadIdx.y;            // 0..3  : m-group (one wave each)

    // XCD-chunked swizzle: 4032 blocks = 8 XCDs x 504 (bijective).
    // Consecutive-mb blocks (sharing the 40-row halo) land on one XCD's L2.
    const int bid  = blockIdx.x;           // 0..4031
    const int xcd  = bid & 7;
    const int slot = bid >> 3;
    const int n    = xcd * 504 + slot;     // linear id, mb-fastest
    const int mb   = n % 63;               // 0..62 : m-block
    const int rest = n / 63;               // 0..63
    const int dh   = rest & 1;             // 0..1  : d-half
    const int b    = rest >> 1;            // 0..31 : batch

    const int m0 = (mb * 4 + mg) * M_;
    if (m0 >= S_) return;                  // tail wave slots

    const int d = (dh * 64 + d4) * 4;
    const float* xb = x + (size_t)b * T_ * D_ + d;
    const float* fb = filt + d;
    float*       ob = out + (size_t)b * T_ * D_ + d;

    // Interior iff every stream index is in [0, S_): E spans [m0-20, m0+23].
    const bool interior = (m0 >= 20) && (m0 <= S_ - M_ - 20);
    if (interior) fsmn_body<false>(xb, fb, ob, m0);
    else          fsmn_body<true >(xb, fb, ob, m0);
}

extern "C" void kernel_launch(void* const* d_in, const int* in_sizes, int n_in,
                              void* d_out, int out_size, void* d_ws, size_t ws_size,
                              hipStream_t stream) {
    const float* x    = (const float*)d_in[0];
    const float* filt = (const float*)d_in[1];
    float*       out  = (float*)d_out;

    dim3 block(64, 4, 1);
    // 63 m-blocks (16 m per block) x 2 d-halves x 32 batches = 4032 blocks.
    dim3 grid(4032, 1, 1);
    hipLaunchKernelGGL(fsmn_kernel, grid, block, 0, stream, x, filt, out);
}